// Round 17
// baseline (124.562 us; speedup 1.0000x reference)
//
#include <hip/hip_runtime.h>
#include <hip/hip_bf16.h>

#define NTOK 2048      // B*T
#define DM 1024
#define NEXP 8
#define FFN 4096
#define BM 64
#define BN 64
#define BK 64
#define ASTR 72        // A-tile LDS row stride (bf16)
#define MT1 8          // gemm1 m-tile slots (8*64=512 cap, grid-stride beyond)
#define MT2 4          // gemm2 m-tile slots
#define G2_SPLIT 8

typedef __bf16 bf16x8 __attribute__((ext_vector_type(8)));
typedef __bf16 bf16x4 __attribute__((ext_vector_type(4)));
typedef float f32x4 __attribute__((ext_vector_type(4)));

__device__ __forceinline__ bf16x8 zero8() {
  bf16x8 z;
#pragma unroll
  for (int j = 0; j < 8; j++) z[j] = (__bf16)0.f;
  return z;
}

// Swizzled B-tile read (row stride 144 B, XOR 16B-block by row>>3): verified R5-R16.
__device__ __forceinline__ bf16x8 readB(const char* BsB, int row, int kh, int quad) {
  return *(const bf16x8*)(BsB + row * 144 +
                          ((((kh << 2) + quad) ^ (row >> 3)) << 4));
}

// Transpose-free B staging (verified R11-R16): thread (w,quad,r16) holds rows
// k=w*16+quad*4+j (j=0..3), cols r16*4..+3; column c's k-run stored as bf16x4.
#define STOREB4() do {                                                   \
    const float* p0 = (const float*)&br0;                                \
    const float* p1 = (const float*)&br1;                                \
    const float* p2 = (const float*)&br2;                                \
    const float* p3 = (const float*)&br3;                                \
    _Pragma("unroll") for (int c = 0; c < 4; ++c) {                      \
      bf16x4 o;                                                          \
      o[0] = (__bf16)p0[c]; o[1] = (__bf16)p1[c];                        \
      o[2] = (__bf16)p2[c]; o[3] = (__bf16)p3[c];                        \
      *(bf16x4*)(bb + c * 144) = o;                                      \
    } } while (0)

// In-kernel prefix over 8 counts (L2-hot; replaces scan_offs launch).
__device__ __forceinline__ int hbase_of(const int* counts, int e) {
  int s = 0;
#pragma unroll
  for (int i = 0; i < NEXP; i++) s += (i < e) ? counts[i] : 0;
  return s;
}

// ---------------- router + bf16 compact gather ----------------
__global__ __launch_bounds__(256) void router_gather(
    const float* __restrict__ x, const int* __restrict__ mask,
    const float* __restrict__ rw, int* __restrict__ counts,
    int* __restrict__ tlist, float* __restrict__ gateE,
    __bf16* __restrict__ xg)
{
  int wid = threadIdx.x >> 6, lane = threadIdx.x & 63;
  int t = blockIdx.x * 4 + wid;

  const float* xr = x + (size_t)t * DM;
  float xv[16];
#pragma unroll
  for (int i = 0; i < 4; i++) {
    const float4 v = *(const float4*)(xr + lane * 16 + i * 4);
    xv[i * 4 + 0] = v.x; xv[i * 4 + 1] = v.y;
    xv[i * 4 + 2] = v.z; xv[i * 4 + 3] = v.w;
  }

  float acc[NEXP];
#pragma unroll
  for (int e = 0; e < NEXP; e++) {
    float a = 0.f;
    const float* rwe = rw + e * DM + lane * 16;
#pragma unroll
    for (int i = 0; i < 4; i++) {
      const float4 r = *(const float4*)(rwe + i * 4);
      a += xv[i*4+0]*r.x + xv[i*4+1]*r.y + xv[i*4+2]*r.z + xv[i*4+3]*r.w;
    }
    acc[e] = a;
  }
#pragma unroll
  for (int e = 0; e < NEXP; e++)
#pragma unroll
    for (int s = 1; s < 64; s <<= 1) acc[e] += __shfl_xor(acc[e], s, 64);

  int pack = -1;
  if (lane == 0 && mask[t] != 0) {
    float m = acc[0]; int am = 0;
#pragma unroll
    for (int e = 1; e < NEXP; e++) if (acc[e] > m) { m = acc[e]; am = e; }
    float s = 0.f;
#pragma unroll
    for (int e = 0; e < NEXP; e++) s += __expf(acc[e] - m);
    int slot = atomicAdd(&counts[am], 1);
    tlist[am * NTOK + slot] = t;
    gateE[am * NTOK + slot] = 1.0f / s;
    pack = am * NTOK + slot;
  }
  pack = __shfl(pack, 0, 64);
  if (pack >= 0) {
    __bf16* dst = xg + (size_t)pack * DM + lane * 16;
    bf16x8 o0, o1;
#pragma unroll
    for (int j = 0; j < 8; j++) {
      o0[j] = (__bf16)xv[j];
      o1[j] = (__bf16)xv[8 + j];
    }
    *(bf16x8*)dst = o0;
    *(bf16x8*)(dst + 8) = o1;
  }
}

// ---- GEMM1: hc[hbase+slot] = relu(xg_e @ w1[e]), BM=64 (R11/R16 layout) ----
// blockIdx: bits0-5 = nt, bits6-8 = mt, bits9+ = e (experts spread over XCDs).
__global__ __launch_bounds__(256) void moe_gemm1(
    const __bf16* __restrict__ xg, const float* __restrict__ w1,
    const int* __restrict__ counts, __bf16* __restrict__ hc)
{
  int bx = blockIdx.x;
  int nt = bx & 63, mt = (bx >> 6) & (MT1 - 1), e = bx >> 9;
  int cnt = counts[e];
  if (mt * BM >= cnt) return;
  int n0 = nt * BN;
  int hbase = hbase_of(counts, e);

  __shared__ __bf16 As[BM][ASTR];
  __shared__ char   Bs[64 * 144];

  int tid = threadIdx.x, lane = tid & 63, w = tid >> 6;
  int wm = w >> 1, wn = w & 1;
  int r16 = lane & 15, quad = lane >> 4;
  int rsw = r16 >> 1;
  char* bb = Bs + (r16 << 2) * 144 +
             (((((w << 1) + (quad >> 1))) ^ rsw) << 4) + ((quad & 1) << 3);

  const __bf16* xge = xg + (size_t)e * NTOK * DM;
  const float*  w1e = w1 + (size_t)e * DM * FFN;

  int ar = tid >> 2;
  int ak = (tid & 3) << 4;
  const float* bptr = w1e + (size_t)(w * 16 + quad * 4) * FFN + n0 + (r16 << 2);

  bf16x8 a0r, a1r;
  float4 br0, br1, br2, br3;

#define LOADG1(kb) do {                                                   \
    a0r = av ? *(const bf16x8*)(aptr + (kb))     : zero8();               \
    a1r = av ? *(const bf16x8*)(aptr + (kb) + 8) : zero8();               \
    br0 = *(const float4*)(bptr + (size_t)((kb) + 0) * FFN);              \
    br1 = *(const float4*)(bptr + (size_t)((kb) + 1) * FFN);              \
    br2 = *(const float4*)(bptr + (size_t)((kb) + 2) * FFN);              \
    br3 = *(const float4*)(bptr + (size_t)((kb) + 3) * FFN);              \
  } while (0)

  for (int m0 = mt * BM; m0 < cnt; m0 += MT1 * BM) {
    bool av = (m0 + ar) < cnt;
    const __bf16* aptr = xge + (size_t)(m0 + ar) * DM + ak;

    f32x4 acc[2][2] = {};
    LOADG1(0);
    const int T = DM / BK;   // 16
    for (int t = 0; t < T; t++) {
      *(bf16x8*)&As[ar][ak]     = a0r;
      *(bf16x8*)&As[ar][ak + 8] = a1r;
      STOREB4();
      __syncthreads();
      if (t + 1 < T) LOADG1((t + 1) * BK);   // in flight during MFMA phase
#pragma unroll
      for (int kh = 0; kh < 2; kh++) {
        int ks = kh * 32 + (quad << 3);
        bf16x8 aA = *(const bf16x8*)&As[wm * 32 + r16][ks];
        bf16x8 aB = *(const bf16x8*)&As[wm * 32 + 16 + r16][ks];
        bf16x8 bA = readB(Bs, wn * 32 + r16, kh, quad);
        bf16x8 bB = readB(Bs, wn * 32 + 16 + r16, kh, quad);
        acc[0][0] = __builtin_amdgcn_mfma_f32_16x16x32_bf16(aA, bA, acc[0][0], 0, 0, 0);
        acc[0][1] = __builtin_amdgcn_mfma_f32_16x16x32_bf16(aA, bB, acc[0][1], 0, 0, 0);
        acc[1][0] = __builtin_amdgcn_mfma_f32_16x16x32_bf16(aB, bA, acc[1][0], 0, 0, 0);
        acc[1][1] = __builtin_amdgcn_mfma_f32_16x16x32_bf16(aB, bB, acc[1][1], 0, 0, 0);
      }
      __syncthreads();
    }

#pragma unroll
    for (int mf = 0; mf < 2; mf++) {
#pragma unroll
      for (int i = 0; i < 4; i++) {
        int row = wm * 32 + mf * 16 + (quad << 2) + i;
        if (m0 + row < cnt) {
          __bf16* hp = hc + (size_t)(hbase + m0 + row) * FFN + n0 + wn * 32 + r16;
          hp[0]  = (__bf16)fmaxf(acc[mf][0][i], 0.f);
          hp[16] = (__bf16)fmaxf(acc[mf][1][i], 0.f);
        }
      }
    }
    __syncthreads();   // LDS reuse guard for next m-tile
  }
#undef LOADG1
}

// ------- GEMM2 (split-K=8): out[tok] += (hc_e @ w2[e]) * gate ----------
// blockIdx: bits0-2 = e (expert->XCD pinning: all 8 splits of e share one
// XCD L2 -> atomic lines stay resident), bits3-6 = nt, bits7-8 = mt,
// bits9+ = sp.
__global__ __launch_bounds__(256) void moe_gemm2(
    const __bf16* __restrict__ hc, const float* __restrict__ w2,
    const int* __restrict__ counts, const int* __restrict__ tlist,
    const float* __restrict__ gateE, float* __restrict__ out)
{
  int bx = blockIdx.x;
  int e = bx & 7, nt = (bx >> 3) & 15, mt = (bx >> 7) & (MT2 - 1), sp = bx >> 9;
  int cnt = counts[e];
  if (mt * BM >= cnt) return;
  int n0 = nt * BN;
  int ksp = sp * (FFN / G2_SPLIT);   // 512-wide K slice
  int hbase = hbase_of(counts, e);

  __shared__ __bf16 As[BM][ASTR];
  __shared__ char   Bs[64 * 144];
  __shared__ int    toks[BM];
  __shared__ float  gts[BM];

  int tid = threadIdx.x, lane = tid & 63, w = tid >> 6;
  int wm = w >> 1, wn = w & 1;
  int r16 = lane & 15, quad = lane >> 4;
  int rsw = r16 >> 1;
  char* bb = Bs + (r16 << 2) * 144 +
             (((((w << 1) + (quad >> 1))) ^ rsw) << 4) + ((quad & 1) << 3);

  const float* w2e = w2 + (size_t)e * FFN * DM;
  int ar = tid >> 2;
  int ak = (tid & 3) << 4;
  const float* bptr = w2e + (size_t)(ksp + w * 16 + quad * 4) * DM + n0 + (r16 << 2);

  bf16x8 a0r, a1r;
  float4 br0, br1, br2, br3;

#define LOADG2(kb) do {                                                   \
    a0r = av ? *(const bf16x8*)(aptr + (kb))     : zero8();               \
    a1r = av ? *(const bf16x8*)(aptr + (kb) + 8) : zero8();               \
    br0 = *(const float4*)(bptr + (size_t)((kb) + 0) * DM);               \
    br1 = *(const float4*)(bptr + (size_t)((kb) + 1) * DM);               \
    br2 = *(const float4*)(bptr + (size_t)((kb) + 2) * DM);               \
    br3 = *(const float4*)(bptr + (size_t)((kb) + 3) * DM);               \
  } while (0)

  for (int m0 = mt * BM; m0 < cnt; m0 += MT2 * BM) {
    if (tid < BM) {
      bool v = (m0 + tid) < cnt;
      toks[tid] = v ? tlist[e * NTOK + m0 + tid] : -1;
      gts[tid]  = v ? gateE[e * NTOK + m0 + tid] : 0.f;
    }
    __syncthreads();

    bool av = (m0 + ar) < cnt;
    // compact A: consecutive arena rows, no token gather in the hot loop
    const __bf16* aptr = hc + (size_t)(hbase + (av ? m0 + ar : 0)) * FFN + ksp + ak;

    f32x4 acc[2][2] = {};
    LOADG2(0);
    const int T = (FFN / G2_SPLIT) / BK;   // 8
    for (int t = 0; t < T; t++) {
      *(bf16x8*)&As[ar][ak]     = a0r;
      *(bf16x8*)&As[ar][ak + 8] = a1r;
      STOREB4();
      __syncthreads();
      if (t + 1 < T) LOADG2((t + 1) * BK);
#pragma unroll
      for (int kh = 0; kh < 2; kh++) {
        int ks = kh * 32 + (quad << 3);
        bf16x8 aA = *(const bf16x8*)&As[wm * 32 + r16][ks];
        bf16x8 aB = *(const bf16x8*)&As[wm * 32 + 16 + r16][ks];
        bf16x8 bA = readB(Bs, wn * 32 + r16, kh, quad);
        bf16x8 bB = readB(Bs, wn * 32 + 16 + r16, kh, quad);
        acc[0][0] = __builtin_amdgcn_mfma_f32_16x16x32_bf16(aA, bA, acc[0][0], 0, 0, 0);
        acc[0][1] = __builtin_amdgcn_mfma_f32_16x16x32_bf16(aA, bB, acc[0][1], 0, 0, 0);
        acc[1][0] = __builtin_amdgcn_mfma_f32_16x16x32_bf16(aB, bA, acc[1][0], 0, 0, 0);
        acc[1][1] = __builtin_amdgcn_mfma_f32_16x16x32_bf16(aB, bB, acc[1][1], 0, 0, 0);
      }
      __syncthreads();
    }

#pragma unroll
    for (int mf = 0; mf < 2; mf++) {
#pragma unroll
      for (int i = 0; i < 4; i++) {
        int row = wm * 32 + mf * 16 + (quad << 2) + i;
        int tok = toks[row];
        if (tok >= 0) {
          float g = gts[row];
          float* op = out + (size_t)tok * DM + n0 + wn * 32 + r16;
          __hip_atomic_fetch_add(op, acc[mf][0][i] * g,
                                 __ATOMIC_RELAXED, __HIP_MEMORY_SCOPE_AGENT);
          __hip_atomic_fetch_add(op + 16, acc[mf][1][i] * g,
                                 __ATOMIC_RELAXED, __HIP_MEMORY_SCOPE_AGENT);
        }
      }
    }
    __syncthreads();   // toks/gts reuse guard for next m-tile
  }
#undef LOADG2
}

extern "C" void kernel_launch(void* const* d_in, const int* in_sizes, int n_in,
                              void* d_out, int out_size, void* d_ws, size_t ws_size,
                              hipStream_t stream) {
  const float* x    = (const float*)d_in[0];
  const int*   mask = (const int*)d_in[1];
  const float* rw   = (const float*)d_in[2];
  const float* w1   = (const float*)d_in[3];
  const float* w2   = (const float*)d_in[4];
  float* out = (float*)d_out;

  char* ws = (char*)d_ws;
  int*    counts = (int*)ws;                                   // @0,      1 KB
  int*    tlist  = (int*)(ws + 1024);                          // @1K,    64 KB
  float*  gateE  = (float*)(ws + 1024 + 65536);                // 64 KB
  __bf16* xg     = (__bf16*)(ws + 139264);                     // @136K,  32 MB
  __bf16* hc     = (__bf16*)(ws + 139264 +
                             (size_t)NEXP * NTOK * DM * 2);    // 16 MB compact h

  hipMemsetAsync(counts, 0, 1024, stream);
  hipMemsetAsync(out, 0, (size_t)out_size * sizeof(float), stream);

  router_gather<<<NTOK / 4, 256, 0, stream>>>(x, mask, rw, counts, tlist, gateE, xg);
  // 8 e (high bits) x 8 m-slots x 64 nt = 4096 blocks, experts spread over XCDs
  moe_gemm1<<<NEXP * MT1 * (FFN / BN), 256, 0, stream>>>(xg, w1, counts, hc);
  // 8 sp x 4 m-slots x 16 nt x 8 e (e low bits -> XCD pinning) = 4096 blocks
  moe_gemm2<<<G2_SPLIT * NEXP * MT2 * (DM / BN), 256, 0, stream>>>(
      hc, w2, counts, tlist, gateE, out);
}

// Round 18
// 113.291 us; speedup vs baseline: 1.0995x; 1.0995x over previous
//
#include <hip/hip_runtime.h>
#include <hip/hip_bf16.h>

#define NTOK 2048      // B*T
#define DM 1024
#define NEXP 8
#define FFN 4096
#define BM 64
#define BN 64
#define BK 64
#define ASTR 72        // A-tile LDS row stride (bf16)
#define MT1 8          // m-tile slots (8*64=512 cap, grid-stride beyond)
#define G2_SPLIT 4

typedef __bf16 bf16x8 __attribute__((ext_vector_type(8)));
typedef __bf16 bf16x4 __attribute__((ext_vector_type(4)));
typedef float f32x4 __attribute__((ext_vector_type(4)));

__device__ __forceinline__ bf16x8 zero8() {
  bf16x8 z;
#pragma unroll
  for (int j = 0; j < 8; j++) z[j] = (__bf16)0.f;
  return z;
}

// Swizzled B-tile read (row stride 144 B, XOR 16B-block by row>>3): verified R5-R17.
__device__ __forceinline__ bf16x8 readB(const char* BsB, int row, int kh, int quad) {
  return *(const bf16x8*)(BsB + row * 144 +
                          ((((kh << 2) + quad) ^ (row >> 3)) << 4));
}

// Transpose-free B staging (verified R11-R17): thread (w,quad,r16) holds rows
// k=w*16+quad*4+j (j=0..3), cols r16*4..+3; column c's k-run stored as bf16x4.
#define STOREB4() do {                                                   \
    const float* p0 = (const float*)&br0;                                \
    const float* p1 = (const float*)&br1;                                \
    const float* p2 = (const float*)&br2;                                \
    const float* p3 = (const float*)&br3;                                \
    _Pragma("unroll") for (int c = 0; c < 4; ++c) {                      \
      bf16x4 o;                                                          \
      o[0] = (__bf16)p0[c]; o[1] = (__bf16)p1[c];                        \
      o[2] = (__bf16)p2[c]; o[3] = (__bf16)p3[c];                        \
      *(bf16x4*)(bb + c * 144) = o;                                      \
    } } while (0)

// ---------------- router + bf16 compact gather ----------------
__global__ __launch_bounds__(256) void router_gather(
    const float* __restrict__ x, const int* __restrict__ mask,
    const float* __restrict__ rw, int* __restrict__ counts,
    int* __restrict__ tlist, float* __restrict__ gateE,
    __bf16* __restrict__ xg)
{
  int wid = threadIdx.x >> 6, lane = threadIdx.x & 63;
  int t = blockIdx.x * 4 + wid;

  const float* xr = x + (size_t)t * DM;
  float xv[16];
#pragma unroll
  for (int i = 0; i < 4; i++) {
    const float4 v = *(const float4*)(xr + lane * 16 + i * 4);
    xv[i * 4 + 0] = v.x; xv[i * 4 + 1] = v.y;
    xv[i * 4 + 2] = v.z; xv[i * 4 + 3] = v.w;
  }

  float acc[NEXP];
#pragma unroll
  for (int e = 0; e < NEXP; e++) {
    float a = 0.f;
    const float* rwe = rw + e * DM + lane * 16;
#pragma unroll
    for (int i = 0; i < 4; i++) {
      const float4 r = *(const float4*)(rwe + i * 4);
      a += xv[i*4+0]*r.x + xv[i*4+1]*r.y + xv[i*4+2]*r.z + xv[i*4+3]*r.w;
    }
    acc[e] = a;
  }
#pragma unroll
  for (int e = 0; e < NEXP; e++)
#pragma unroll
    for (int s = 1; s < 64; s <<= 1) acc[e] += __shfl_xor(acc[e], s, 64);

  int pack = -1;
  if (lane == 0 && mask[t] != 0) {
    float m = acc[0]; int am = 0;
#pragma unroll
    for (int e = 1; e < NEXP; e++) if (acc[e] > m) { m = acc[e]; am = e; }
    float s = 0.f;
#pragma unroll
    for (int e = 0; e < NEXP; e++) s += __expf(acc[e] - m);
    int slot = atomicAdd(&counts[am], 1);
    tlist[am * NTOK + slot] = t;
    gateE[am * NTOK + slot] = 1.0f / s;
    pack = am * NTOK + slot;
  }
  pack = __shfl(pack, 0, 64);
  if (pack >= 0) {
    __bf16* dst = xg + (size_t)pack * DM + lane * 16;
    bf16x8 o0, o1;
#pragma unroll
    for (int j = 0; j < 8; j++) {
      o0[j] = (__bf16)xv[j];
      o1[j] = (__bf16)xv[8 + j];
    }
    *(bf16x8*)dst = o0;
    *(bf16x8*)(dst + 8) = o1;
  }
}

// ---------------- prefix-sum of counts -> compact arena offsets -------------
__global__ void scan_offs(const int* __restrict__ counts, int* __restrict__ offs) {
  if (threadIdx.x == 0) {
    int s = 0;
#pragma unroll
    for (int e = 0; e < NEXP; e++) { offs[e] = s; s += counts[e]; }
  }
}

// ---- GEMM1: hc[offs[e]+slot] = relu(xg_e @ w1[e]), BM=64 (R11 layout) ------
// blockIdx: bits0-5 = nt, bits6-8 = mt, bits9+ = e (experts spread over XCDs).
__global__ __launch_bounds__(256) void moe_gemm1(
    const __bf16* __restrict__ xg, const float* __restrict__ w1,
    const int* __restrict__ counts, const int* __restrict__ offs,
    __bf16* __restrict__ hc)
{
  int bx = blockIdx.x;
  int nt = bx & 63, mt = (bx >> 6) & (MT1 - 1), e = bx >> 9;
  int cnt = counts[e];
  if (mt * BM >= cnt) return;
  int n0 = nt * BN;
  int hbase = offs[e];

  __shared__ __bf16 As[BM][ASTR];
  __shared__ char   Bs[64 * 144];

  int tid = threadIdx.x, lane = tid & 63, w = tid >> 6;
  int wm = w >> 1, wn = w & 1;
  int r16 = lane & 15, quad = lane >> 4;
  int rsw = r16 >> 1;
  char* bb = Bs + (r16 << 2) * 144 +
             (((((w << 1) + (quad >> 1))) ^ rsw) << 4) + ((quad & 1) << 3);

  const __bf16* xge = xg + (size_t)e * NTOK * DM;
  const float*  w1e = w1 + (size_t)e * DM * FFN;

  int ar = tid >> 2;
  int ak = (tid & 3) << 4;
  const float* bptr = w1e + (size_t)(w * 16 + quad * 4) * FFN + n0 + (r16 << 2);

  bf16x8 a0r, a1r;
  float4 br0, br1, br2, br3;

#define LOADG1(kb) do {                                                   \
    a0r = av ? *(const bf16x8*)(aptr + (kb))     : zero8();               \
    a1r = av ? *(const bf16x8*)(aptr + (kb) + 8) : zero8();               \
    br0 = *(const float4*)(bptr + (size_t)((kb) + 0) * FFN);              \
    br1 = *(const float4*)(bptr + (size_t)((kb) + 1) * FFN);              \
    br2 = *(const float4*)(bptr + (size_t)((kb) + 2) * FFN);              \
    br3 = *(const float4*)(bptr + (size_t)((kb) + 3) * FFN);              \
  } while (0)

  for (int m0 = mt * BM; m0 < cnt; m0 += MT1 * BM) {
    bool av = (m0 + ar) < cnt;
    const __bf16* aptr = xge + (size_t)(m0 + ar) * DM + ak;

    f32x4 acc[2][2] = {};
    LOADG1(0);
    const int T = DM / BK;   // 16
    for (int t = 0; t < T; t++) {
      *(bf16x8*)&As[ar][ak]     = a0r;
      *(bf16x8*)&As[ar][ak + 8] = a1r;
      STOREB4();
      __syncthreads();
      if (t + 1 < T) LOADG1((t + 1) * BK);   // in flight during MFMA phase
#pragma unroll
      for (int kh = 0; kh < 2; kh++) {
        int ks = kh * 32 + (quad << 3);
        bf16x8 aA = *(const bf16x8*)&As[wm * 32 + r16][ks];
        bf16x8 aB = *(const bf16x8*)&As[wm * 32 + 16 + r16][ks];
        bf16x8 bA = readB(Bs, wn * 32 + r16, kh, quad);
        bf16x8 bB = readB(Bs, wn * 32 + 16 + r16, kh, quad);
        acc[0][0] = __builtin_amdgcn_mfma_f32_16x16x32_bf16(aA, bA, acc[0][0], 0, 0, 0);
        acc[0][1] = __builtin_amdgcn_mfma_f32_16x16x32_bf16(aA, bB, acc[0][1], 0, 0, 0);
        acc[1][0] = __builtin_amdgcn_mfma_f32_16x16x32_bf16(aB, bA, acc[1][0], 0, 0, 0);
        acc[1][1] = __builtin_amdgcn_mfma_f32_16x16x32_bf16(aB, bB, acc[1][1], 0, 0, 0);
      }
      __syncthreads();
    }

#pragma unroll
    for (int mf = 0; mf < 2; mf++) {
#pragma unroll
      for (int i = 0; i < 4; i++) {
        int row = wm * 32 + mf * 16 + (quad << 2) + i;
        if (m0 + row < cnt) {
          __bf16* hp = hc + (size_t)(hbase + m0 + row) * FFN + n0 + wn * 32 + r16;
          hp[0]  = (__bf16)fmaxf(acc[mf][0][i], 0.f);
          hp[16] = (__bf16)fmaxf(acc[mf][1][i], 0.f);
        }
      }
    }
    __syncthreads();   // LDS reuse guard for next m-tile
  }
#undef LOADG1
}

// ------- GEMM2 (split-K=4): out[tok] += (hc_e @ w2[e]) * gate ----------
// blockIdx: bits0-2 = e (expert->XCD pinning), bits3-6 = nt, bits7-9 = mt,
// bits10+ = sp.  (R15/R16 layout, verified fast.)
__global__ __launch_bounds__(256) void moe_gemm2(
    const __bf16* __restrict__ hc, const float* __restrict__ w2,
    const int* __restrict__ counts, const int* __restrict__ offs,
    const int* __restrict__ tlist, const float* __restrict__ gateE,
    float* __restrict__ out)
{
  int bx = blockIdx.x;
  int e = bx & 7, nt = (bx >> 3) & 15, mt = (bx >> 7) & 7, sp = bx >> 10;
  int cnt = counts[e];
  if (mt * BM >= cnt) return;
  int n0 = nt * BN;
  int ksp = sp * (FFN / G2_SPLIT);
  int hbase = offs[e];

  __shared__ __bf16 As[BM][ASTR];
  __shared__ char   Bs[64 * 144];
  __shared__ int    toks[BM];
  __shared__ float  gts[BM];

  int tid = threadIdx.x, lane = tid & 63, w = tid >> 6;
  int wm = w >> 1, wn = w & 1;
  int r16 = lane & 15, quad = lane >> 4;
  int rsw = r16 >> 1;
  char* bb = Bs + (r16 << 2) * 144 +
             (((((w << 1) + (quad >> 1))) ^ rsw) << 4) + ((quad & 1) << 3);

  const float* w2e = w2 + (size_t)e * FFN * DM;
  int ar = tid >> 2;
  int ak = (tid & 3) << 4;
  const float* bptr = w2e + (size_t)(ksp + w * 16 + quad * 4) * DM + n0 + (r16 << 2);

  bf16x8 a0r, a1r;
  float4 br0, br1, br2, br3;

#define LOADG2(kb) do {                                                   \
    a0r = av ? *(const bf16x8*)(aptr + (kb))     : zero8();               \
    a1r = av ? *(const bf16x8*)(aptr + (kb) + 8) : zero8();               \
    br0 = *(const float4*)(bptr + (size_t)((kb) + 0) * DM);               \
    br1 = *(const float4*)(bptr + (size_t)((kb) + 1) * DM);               \
    br2 = *(const float4*)(bptr + (size_t)((kb) + 2) * DM);               \
    br3 = *(const float4*)(bptr + (size_t)((kb) + 3) * DM);               \
  } while (0)

  for (int m0 = mt * BM; m0 < cnt; m0 += MT1 * BM) {
    if (tid < BM) {
      bool v = (m0 + tid) < cnt;
      toks[tid] = v ? tlist[e * NTOK + m0 + tid] : -1;
      gts[tid]  = v ? gateE[e * NTOK + m0 + tid] : 0.f;
    }
    __syncthreads();

    bool av = (m0 + ar) < cnt;
    // compact A: consecutive arena rows, no token gather in the hot loop
    const __bf16* aptr = hc + (size_t)(hbase + (av ? m0 + ar : 0)) * FFN + ksp + ak;

    f32x4 acc[2][2] = {};
    LOADG2(0);
    const int T = (FFN / G2_SPLIT) / BK;   // 16
    for (int t = 0; t < T; t++) {
      *(bf16x8*)&As[ar][ak]     = a0r;
      *(bf16x8*)&As[ar][ak + 8] = a1r;
      STOREB4();
      __syncthreads();
      if (t + 1 < T) LOADG2((t + 1) * BK);
#pragma unroll
      for (int kh = 0; kh < 2; kh++) {
        int ks = kh * 32 + (quad << 3);
        bf16x8 aA = *(const bf16x8*)&As[wm * 32 + r16][ks];
        bf16x8 aB = *(const bf16x8*)&As[wm * 32 + 16 + r16][ks];
        bf16x8 bA = readB(Bs, wn * 32 + r16, kh, quad);
        bf16x8 bB = readB(Bs, wn * 32 + 16 + r16, kh, quad);
        acc[0][0] = __builtin_amdgcn_mfma_f32_16x16x32_bf16(aA, bA, acc[0][0], 0, 0, 0);
        acc[0][1] = __builtin_amdgcn_mfma_f32_16x16x32_bf16(aA, bB, acc[0][1], 0, 0, 0);
        acc[1][0] = __builtin_amdgcn_mfma_f32_16x16x32_bf16(aB, bA, acc[1][0], 0, 0, 0);
        acc[1][1] = __builtin_amdgcn_mfma_f32_16x16x32_bf16(aB, bB, acc[1][1], 0, 0, 0);
      }
      __syncthreads();
    }

#pragma unroll
    for (int mf = 0; mf < 2; mf++) {
#pragma unroll
      for (int i = 0; i < 4; i++) {
        int row = wm * 32 + mf * 16 + (quad << 2) + i;
        int tok = toks[row];
        if (tok >= 0) {
          float g = gts[row];
          float* op = out + (size_t)tok * DM + n0 + wn * 32 + r16;
          __hip_atomic_fetch_add(op, acc[mf][0][i] * g,
                                 __ATOMIC_RELAXED, __HIP_MEMORY_SCOPE_AGENT);
          __hip_atomic_fetch_add(op + 16, acc[mf][1][i] * g,
                                 __ATOMIC_RELAXED, __HIP_MEMORY_SCOPE_AGENT);
        }
      }
    }
    __syncthreads();   // toks/gts reuse guard for next m-tile
  }
#undef LOADG2
}

extern "C" void kernel_launch(void* const* d_in, const int* in_sizes, int n_in,
                              void* d_out, int out_size, void* d_ws, size_t ws_size,
                              hipStream_t stream) {
  const float* x    = (const float*)d_in[0];
  const int*   mask = (const int*)d_in[1];
  const float* rw   = (const float*)d_in[2];
  const float* w1   = (const float*)d_in[3];
  const float* w2   = (const float*)d_in[4];
  float* out = (float*)d_out;

  char* ws = (char*)d_ws;
  int*    counts = (int*)ws;                                   // @0,      1 KB
  int*    offs   = (int*)(ws + 1024);                          // @1K,     1 KB
  int*    tlist  = (int*)(ws + 2048);                          // @2K,    64 KB
  float*  gateE  = (float*)(ws + 2048 + 65536);                // 64 KB
  __bf16* xg     = (__bf16*)(ws + 139264);                     // @136K,  32 MB
  __bf16* hc     = (__bf16*)(ws + 139264 +
                             (size_t)NEXP * NTOK * DM * 2);    // 16 MB compact h

  hipMemsetAsync(counts, 0, 1024, stream);
  hipMemsetAsync(out, 0, (size_t)out_size * sizeof(float), stream);

  router_gather<<<NTOK / 4, 256, 0, stream>>>(x, mask, rw, counts, tlist, gateE, xg);
  scan_offs<<<1, 64, 0, stream>>>(counts, offs);
  // 8 e (high bits) x 8 m-slots x 64 nt = 4096 blocks, experts spread over XCDs
  moe_gemm1<<<NEXP * MT1 * (FFN / BN), 256, 0, stream>>>(xg, w1, counts, offs, hc);
  // 4 sp x 8 m-slots x 16 nt x 8 e (e low bits -> XCD pinning) = 4096 blocks
  moe_gemm2<<<G2_SPLIT * NEXP * MT1 * (DM / BN), 256, 0, stream>>>(
      hc, w2, counts, offs, tlist, gateE, out);
}